// Round 1
// 488.005 us; speedup vs baseline: 1.2598x; 1.2598x over previous
//
#include <hip/hip_runtime.h>

#define N_USER 100000
#define N_ITEM 100000
#define N_NODES 200000
#define NNZ 6400000
#define EMB 64
#define BATCH 1024
#define B3 (3 * BATCH)   // 3072 output rows (users, pos, neg)

typedef __attribute__((ext_vector_type(8))) short bf16x8;   // 8 bf16 = 4 VGPRs
typedef __attribute__((ext_vector_type(4))) float f32x4;    // MFMA 16x16 acc

// ---------------------------------------------------------------------------
// Frontier-sparsified NGCF:
//   layer 1: full propagation (all 200k rows, 6.4M nnz)
//   layer 2: only rows in  active2 = batch ∪ neighbors(batch)  (~80k rows)
//   layer 3: only the 3072 batch rows (~98k nnz), batch-position-indexed
// active2 built once by flag-dedupe + atomic append (order irrelevant: rows
// independent). All grids static (graph-capture safe); dynamic count handled
// by wave-uniform early exit. Dedupe caps count at N_NODES so the full-size
// grid for layer 2 can never under-cover.
// ---------------------------------------------------------------------------

// f32 -> bf16 (RNE), raw ushort bits
__device__ __forceinline__ unsigned short f2bf(float f) {
    unsigned int b = __builtin_bit_cast(unsigned int, f);
    b += 0x7FFFu + ((b >> 16) & 1u);
    return (unsigned short)(b >> 16);
}
__device__ __forceinline__ float bf2f(unsigned short u) {
    return __builtin_bit_cast(float, (unsigned int)u << 16);
}
__device__ __forceinline__ unsigned int pack2(float lo, float hi) {
    return ((unsigned int)f2bf(hi) << 16) | f2bf(lo);
}

// elementwise product of two bf16 fragments (A-layouts align), f32 math
__device__ __forceinline__ bf16x8 mul_bf(bf16x8 a, bf16x8 b) {
    bf16x8 r;
#pragma unroll
    for (int j = 0; j < 8; ++j) {
        float f = bf2f((unsigned short)a[j]) * bf2f((unsigned short)b[j]);
        r[j] = (short)f2bf(f);
    }
    return r;
}

// row_ptr[r] = lower_bound(adj_row, r); every r in [0, N_NODES] written once.
__global__ void build_row_ptr(const int* __restrict__ row, int* __restrict__ row_ptr) {
    int i = blockIdx.x * blockDim.x + threadIdx.x;
    if (i >= NNZ) return;
    int b = row[i];
    int a = (i == 0) ? -1 : row[i - 1];
    for (int r = a + 1; r <= b; ++r) row_ptr[r] = i;
    if (i == NNZ - 1) {
        for (int r = b + 1; r <= N_NODES; ++r) row_ptr[r] = NNZ;
    }
}

// ego_h = bf16([user_emb ; item_emb]); float4 in, 4xbf16 (uint2) out
__global__ void concat_ego(const float* __restrict__ ue, const float* __restrict__ ie,
                           unsigned short* __restrict__ ego_h) {
    int i = blockIdx.x * blockDim.x + threadIdx.x;   // float4 index
    const int nu4 = N_USER * EMB / 4;
    const int tot4 = N_NODES * EMB / 4;
    if (i >= tot4) return;
    float4 v = (i < nu4) ? ((const float4*)ue)[i] : ((const float4*)ie)[i - nu4];
    uint2 o;
    o.x = pack2(v.x, v.y);
    o.y = pack2(v.z, v.w);
    ((uint2*)ego_h)[i] = o;
}

// pack the 6 64x64 f32 weight matrices into MFMA B-fragment layout (bf16).
__global__ void prep_wfrags(const float* __restrict__ W0, const float* __restrict__ W1,
                            const float* __restrict__ W2, const float* __restrict__ W3,
                            const float* __restrict__ W4, const float* __restrict__ W5,
                            unsigned short* __restrict__ wfrag) {
    int m = blockIdx.x >> 3;
    int t = (blockIdx.x >> 1) & 3, c = blockIdx.x & 1;
    const float* W = m == 0 ? W0 : m == 1 ? W1 : m == 2 ? W2 : m == 3 ? W3 : m == 4 ? W4 : W5;
    int l = threadIdx.x, quad = l >> 4, n = l & 15;
    unsigned short* dst = wfrag + ((size_t)blockIdx.x * 64 + l) * 8;
#pragma unroll
    for (int j = 0; j < 8; ++j)
        dst[j] = f2bf(W[(c * 32 + quad * 8 + j) * 64 + t * 16 + n]);
}

__device__ __forceinline__ int batch_node(const int* users, const int* pos,
                                          const int* neg, int b) {
    int t = b >> 10, idx = b & 1023;
    if (t == 0) return users[idx];
    if (t == 1) return N_USER + pos[idx];
    return N_USER + neg[idx];
}

// layer-0 output columns: exact f32 from the original input embeddings
__global__ void gather_layer0(const int* __restrict__ users, const int* __restrict__ pos,
                              const int* __restrict__ neg, const float* __restrict__ ue,
                              const float* __restrict__ ie, float* __restrict__ out) {
    int b = blockIdx.x;
    int node = batch_node(users, pos, neg, b);
    float v = (node < N_USER) ? ue[(size_t)node * EMB + threadIdx.x]
                              : ie[(size_t)(node - N_USER) * EMB + threadIdx.x];
    out[(size_t)b * 256 + threadIdx.x] = v;
}

// ---- frontier construction --------------------------------------------------

__global__ void zero_flags(int* __restrict__ flags) {
    int i = blockIdx.x * blockDim.x + threadIdx.x;
    if (i < N_NODES + 4) flags[i] = 0;    // flags + cnt (cnt = flags[N_NODES])
}

// wave = one batch entry; lanes split its nnz. Dedupe via flags, append to
// list2. Compiler coalesces atomicAdd(cnt,1) into one per-wave add (G12).
__global__ __launch_bounds__(256) void build_frontier(
        const int* __restrict__ users, const int* __restrict__ pos,
        const int* __restrict__ neg, const int* __restrict__ row_ptr,
        const int* __restrict__ col, int* __restrict__ flags,
        int* __restrict__ list2, int* __restrict__ cnt) {
    int w = (blockIdx.x * blockDim.x + threadIdx.x) >> 6;
    int lane = threadIdx.x & 63;
    if (w >= B3) return;
    int node = batch_node(users, pos, neg, w);
    if (lane == 0) {
        if (atomicOr(&flags[node], 1) == 0) list2[atomicAdd(cnt, 1)] = node;
    }
    int j0 = row_ptr[node], j1 = row_ptr[node + 1];
    for (int j = j0 + lane; j < j1; j += 64) {
        int c = col[j];
        if (atomicOr(&flags[c], 1) == 0) list2[atomicAdd(cnt, 1)] = c;
    }
}

// ---- SpMM core --------------------------------------------------------------

// CSR SpMM, quarter-wave gather: wave = 1 row; 16 lanes x uint2 (4 dims) cover
// the 64-dim row, so ONE dwordx2 gather serves 4 nnz. Chunk of 32 (col,val)
// staged coalesced, per-quarter broadcast via ds_bpermute.
__device__ __forceinline__ void spmm_row(
        int row, int lane, const int* __restrict__ row_ptr,
        const int* __restrict__ col, const float* __restrict__ val,
        const unsigned short* __restrict__ xh, unsigned short* __restrict__ dst) {
    int q = lane >> 4, p = lane & 15;
    int q4 = q << 2;
    unsigned p4 = (unsigned)p * 4u;
    int j0 = row_ptr[row], j1 = row_ptr[row + 1];
    float a0 = 0.f, a1 = 0.f, a2 = 0.f, a3 = 0.f;
    for (int j = j0; j < j1; j += 32) {
        int jl = j + (lane & 31);           // lanes 32..63 duplicate 0..31
        bool ok = jl < j1;
        int cc = ok ? __builtin_nontemporal_load(col + jl) : 0;
        int vv = ok ? __builtin_bit_cast(int, __builtin_nontemporal_load(val + jl))
                    : 0;
        int n = j1 - j;
#pragma unroll
        for (int g = 0; g < 4; ++g) {
            if (g * 8 >= n) break;          // wave-uniform exit
#pragma unroll
            for (int s = 0; s < 2; ++s) {
                const int t = g * 8 + s * 4;          // this step: nnz t..t+3
                int   ct = __builtin_amdgcn_ds_bpermute(q4 + t * 4, cc);
                float vt = __builtin_bit_cast(float,
                            __builtin_amdgcn_ds_bpermute(q4 + t * 4, vv));
                unsigned idx = (unsigned)ct * 64u + p4;   // ushort index
                uint2 d = *(const uint2*)(xh + idx);
                float f0 = __builtin_bit_cast(float, d.x << 16);
                float f1 = __builtin_bit_cast(float, d.x & 0xffff0000u);
                float f2 = __builtin_bit_cast(float, d.y << 16);
                float f3 = __builtin_bit_cast(float, d.y & 0xffff0000u);
                a0 = fmaf(vt, f0, a0);
                a1 = fmaf(vt, f1, a1);
                a2 = fmaf(vt, f2, a2);
                a3 = fmaf(vt, f3, a3);
            }
        }
    }
    a0 += __shfl_xor(a0, 16); a0 += __shfl_xor(a0, 32);
    a1 += __shfl_xor(a1, 16); a1 += __shfl_xor(a1, 32);
    a2 += __shfl_xor(a2, 16); a2 += __shfl_xor(a2, 32);
    a3 += __shfl_xor(a3, 16); a3 += __shfl_xor(a3, 32);
    if (q == 0) {
        uint2 o;
        o.x = pack2(a0, a1);
        o.y = pack2(a2, a3);
        ((uint2*)dst)[p] = o;               // 16 lanes x 8B = full row
    }
}

__global__ __launch_bounds__(256) void spmm_full(
        const int* __restrict__ row_ptr, const int* __restrict__ col,
        const float* __restrict__ val, const unsigned short* __restrict__ xh,
        unsigned short* __restrict__ yh) {
    int wave = (blockIdx.x * blockDim.x + threadIdx.x) >> 6;
    if (wave >= N_NODES) return;
    spmm_row(wave, threadIdx.x & 63, row_ptr, col, val, xh, yh + (size_t)wave * EMB);
}

__global__ __launch_bounds__(256) void spmm_list(
        const int* __restrict__ row_ptr, const int* __restrict__ col,
        const float* __restrict__ val, const unsigned short* __restrict__ xh,
        unsigned short* __restrict__ yh, const int* __restrict__ list,
        const int* __restrict__ cntp) {
    int wave = (blockIdx.x * blockDim.x + threadIdx.x) >> 6;
    if (wave >= *cntp) return;              // wave-uniform early exit
    int row = list[wave];
    spmm_row(row, threadIdx.x & 63, row_ptr, col, val, xh, yh + (size_t)row * EMB);
}

// layer-3: rows = batch nodes (dupes benign: identical-value writes), output
// is batch-POSITION indexed so downstream needs no dedupe.
__global__ __launch_bounds__(256) void spmm_batch(
        const int* __restrict__ row_ptr, const int* __restrict__ col,
        const float* __restrict__ val, const unsigned short* __restrict__ xh,
        unsigned short* __restrict__ side3, const int* __restrict__ users,
        const int* __restrict__ pos, const int* __restrict__ neg) {
    int wave = (blockIdx.x * blockDim.x + threadIdx.x) >> 6;
    if (wave >= B3) return;
    int row = batch_node(users, pos, neg, wave);
    spmm_row(row, threadIdx.x & 63, row_ptr, col, val, xh, side3 + (size_t)wave * EMB);
}

// ---- dense layer core -------------------------------------------------------

// MFMA: acc[t] = bias + side@Wgc[:,t] + (ego*side)@Wbi[:,t], 16 rows x 64 cols
// per wave. aside/aego are this lane's A-row base pointers (row for n=lane&15).
__device__ __forceinline__ void dense_core(
        const unsigned short* __restrict__ aside,
        const unsigned short* __restrict__ aego,
        const unsigned short* __restrict__ wf, int lane,
        const float* __restrict__ bgc, const float* __restrict__ bbi,
        f32x4 acc[4]) {
    int quad = lane >> 4, n = lane & 15;

    bf16x8 bfrag[2][4][2];
#pragma unroll
    for (int m = 0; m < 2; ++m)
#pragma unroll
        for (int t = 0; t < 4; ++t)
#pragma unroll
            for (int c = 0; c < 2; ++c)
                bfrag[m][t][c] = *(const bf16x8*)(wf + ((size_t)((m * 4 + t) * 2 + c) * 64 + lane) * 8);

#pragma unroll
    for (int t = 0; t < 4; ++t) {
        float bs = bgc[t * 16 + n] + bbi[t * 16 + n];
        acc[t] = (f32x4){bs, bs, bs, bs};
    }

    bf16x8 as0 = *(const bf16x8*)(aside + quad * 8);
    bf16x8 as1 = *(const bf16x8*)(aside + quad * 8 + 32);
    bf16x8 ae0 = *(const bf16x8*)(aego + quad * 8);
    bf16x8 ae1 = *(const bf16x8*)(aego + quad * 8 + 32);
    bf16x8 ap0 = mul_bf(ae0, as0);
    bf16x8 ap1 = mul_bf(ae1, as1);

#pragma unroll
    for (int t = 0; t < 4; ++t) {
        acc[t] = __builtin_amdgcn_mfma_f32_16x16x32_bf16(as0, bfrag[0][t][0], acc[t], 0, 0, 0);
        acc[t] = __builtin_amdgcn_mfma_f32_16x16x32_bf16(as1, bfrag[0][t][1], acc[t], 0, 0, 0);
        acc[t] = __builtin_amdgcn_mfma_f32_16x16x32_bf16(ap0, bfrag[1][t][0], acc[t], 0, 0, 0);
        acc[t] = __builtin_amdgcn_mfma_f32_16x16x32_bf16(ap1, bfrag[1][t][1], acc[t], 0, 0, 0);
    }
}

// full (list==nullptr) or list-sparsified in-place ego update. list is deduped
// so each row is owned by exactly one wave (in-place safe). Partial tail wave
// clamps A-row reads to its own range and suppresses out-of-range writes.
__global__ __launch_bounds__(256) void dense_mfma(
        const unsigned short* __restrict__ side_h,
        unsigned short* __restrict__ ego_h,
        const unsigned short* __restrict__ wf,
        const float* __restrict__ bgc, const float* __restrict__ bbi,
        const int* __restrict__ list, const int* __restrict__ cntp) {
    int wave = threadIdx.x >> 6;
    int lane = threadIdx.x & 63;
    int quad = lane >> 4, n = lane & 15;
    int base = (blockIdx.x * 4 + wave) * 16;
    int cntv = list ? *cntp : N_NODES;
    if (base >= cntv) return;

    int rA = base + n;
    if (list) rA = list[rA < cntv ? rA : cntv - 1];

    f32x4 acc[4];
    dense_core(side_h + (size_t)rA * EMB, ego_h + (size_t)rA * EMB,
               wf, lane, bgc, bbi, acc);

    int rw[4];
#pragma unroll
    for (int i = 0; i < 4; ++i) {
        int r = base + quad * 4 + i;
        rw[i] = (r < cntv) ? (list ? list[r] : r) : -1;
    }
    // epilogue: C/D layout col=lane&15, row=quad*4+reg (m89-verified)
#pragma unroll
    for (int t = 0; t < 4; ++t)
#pragma unroll
        for (int i = 0; i < 4; ++i) {
            if (rw[i] < 0) continue;
            float v = acc[t][i];
            float o = v > 0.f ? v : 0.2f * v;
            ego_h[(size_t)rw[i] * EMB + t * 16 + n] = f2bf(o);
        }
}

// layer-3 dense: batch-position side3 in, f32 ego3 out (never touches ego_h,
// so duplicate batch nodes cannot race the in-place update).
__global__ __launch_bounds__(256) void dense_batch(
        const unsigned short* __restrict__ side3,
        const unsigned short* __restrict__ ego_h,
        const int* __restrict__ users, const int* __restrict__ pos,
        const int* __restrict__ neg, const unsigned short* __restrict__ wf,
        const float* __restrict__ bgc, const float* __restrict__ bbi,
        float* __restrict__ ego3) {
    int wave = threadIdx.x >> 6;
    int lane = threadIdx.x & 63;
    int quad = lane >> 4, n = lane & 15;
    int b0 = blockIdx.x * 64 + wave * 16;
    int bA = b0 + n;
    int nodeA = batch_node(users, pos, neg, bA);

    f32x4 acc[4];
    dense_core(side3 + (size_t)bA * EMB, ego_h + (size_t)nodeA * EMB,
               wf, lane, bgc, bbi, acc);

#pragma unroll
    for (int t = 0; t < 4; ++t)
#pragma unroll
        for (int i = 0; i < 4; ++i) {
            float v = acc[t][i];
            float o = v > 0.f ? v : 0.2f * v;
            ego3[(size_t)(b0 + quad * 4 + i) * EMB + t * 16 + n] = o;
        }
}

// gather batch rows of ego_h (bf16), L2-normalize, write out cols [64*layer,..)
__global__ void gather_norm(const int* __restrict__ users, const int* __restrict__ pos,
                            const int* __restrict__ neg,
                            const unsigned short* __restrict__ ego_h,
                            float* __restrict__ out, int layer) {
    int b = blockIdx.x;
    int lane = threadIdx.x;
    int node = batch_node(users, pos, neg, b);
    float v = bf2f(ego_h[(size_t)node * EMB + lane]);
    float s = v * v;
#pragma unroll
    for (int off = 32; off > 0; off >>= 1) s += __shfl_xor(s, off);
    float n = fmaxf(sqrtf(s), 1e-12f);
    out[(size_t)b * 256 + layer * EMB + lane] = v / n;
}

// layer-3 norm from f32 ego3 (batch-position indexed)
__global__ void gather_norm_b3(const float* __restrict__ ego3, float* __restrict__ out) {
    int b = blockIdx.x;
    int lane = threadIdx.x;
    float v = ego3[(size_t)b * EMB + lane];
    float s = v * v;
#pragma unroll
    for (int off = 32; off > 0; off >>= 1) s += __shfl_xor(s, off);
    float n = fmaxf(sqrtf(s), 1e-12f);
    out[(size_t)b * 256 + 192 + lane] = v / n;
}

extern "C" void kernel_launch(void* const* d_in, const int* in_sizes, int n_in,
                              void* d_out, int out_size, void* d_ws, size_t ws_size,
                              hipStream_t stream) {
    const int*   users    = (const int*)d_in[0];
    const int*   pos      = (const int*)d_in[1];
    const int*   neg      = (const int*)d_in[2];
    const int*   adj_row  = (const int*)d_in[3];
    const int*   adj_col  = (const int*)d_in[4];
    const float* adj_val  = (const float*)d_in[5];
    const float* user_emb = (const float*)d_in[6];
    const float* item_emb = (const float*)d_in[7];
    // d_in[8..19]: W_gc_0, b_gc_0, W_bi_0, b_bi_0, W_gc_1, ... (4 per layer)

    unsigned short* ego_h   = (unsigned short*)d_ws;
    unsigned short* side_h  = ego_h + (size_t)N_NODES * EMB;
    int*            row_ptr = (int*)(side_h + (size_t)N_NODES * EMB);
    unsigned short* wfrag   = (unsigned short*)(row_ptr + 200704);  // 16B-aligned
    int*            flags   = (int*)(wfrag + 6 * 8 * 64 * 8);       // 49152B -> aligned
    int*            cnt     = flags + N_NODES;                       // +4 ints pad
    int*            list2   = cnt + 4;
    unsigned short* side3   = (unsigned short*)(list2 + N_NODES);
    float*          ego3    = (float*)(side3 + (size_t)B3 * EMB);
    float*          out     = (float*)d_out;

    build_row_ptr<<<(NNZ + 255) / 256, 256, 0, stream>>>(adj_row, row_ptr);
    concat_ego<<<(N_NODES * EMB / 4 + 255) / 256, 256, 0, stream>>>(user_emb, item_emb, ego_h);
    prep_wfrags<<<48, 64, 0, stream>>>((const float*)d_in[8], (const float*)d_in[10],
                                       (const float*)d_in[12], (const float*)d_in[14],
                                       (const float*)d_in[16], (const float*)d_in[18], wfrag);
    gather_layer0<<<B3, 64, 0, stream>>>(users, pos, neg, user_emb, item_emb, out);

    zero_flags<<<(N_NODES + 4 + 255) / 256, 256, 0, stream>>>(flags);
    build_frontier<<<B3 / 4, 256, 0, stream>>>(users, pos, neg, row_ptr, adj_col,
                                               flags, list2, cnt);

    // layer 1: full
    {
        const float* bgc = (const float*)d_in[9];
        const float* bbi = (const float*)d_in[11];
        spmm_full<<<N_NODES / 4, 256, 0, stream>>>(row_ptr, adj_col, adj_val, ego_h, side_h);
        dense_mfma<<<N_NODES / 64, 256, 0, stream>>>(side_h, ego_h, wfrag, bgc, bbi,
                                                     nullptr, nullptr);
        gather_norm<<<B3, 64, 0, stream>>>(users, pos, neg, ego_h, out, 1);
    }
    // layer 2: active2 = batch ∪ neighbors(batch)  (early-exit full grids)
    {
        const float* bgc = (const float*)d_in[13];
        const float* bbi = (const float*)d_in[15];
        spmm_list<<<N_NODES / 4, 256, 0, stream>>>(row_ptr, adj_col, adj_val, ego_h,
                                                   side_h, list2, cnt);
        dense_mfma<<<N_NODES / 64, 256, 0, stream>>>(side_h, ego_h,
                                                     wfrag + (size_t)1 * 2 * 8 * 64 * 8,
                                                     bgc, bbi, list2, cnt);
        gather_norm<<<B3, 64, 0, stream>>>(users, pos, neg, ego_h, out, 2);
    }
    // layer 3: batch rows only, batch-position indexed
    {
        const float* bgc = (const float*)d_in[17];
        const float* bbi = (const float*)d_in[19];
        spmm_batch<<<B3 / 4, 256, 0, stream>>>(row_ptr, adj_col, adj_val, ego_h,
                                               side3, users, pos, neg);
        dense_batch<<<B3 / 64, 256, 0, stream>>>(side3, ego_h, users, pos, neg,
                                                 wfrag + (size_t)2 * 2 * 8 * 64 * 8,
                                                 bgc, bbi, ego3);
        gather_norm_b3<<<B3, 64, 0, stream>>>(ego3, out);
    }
}